// Round 5
// baseline (213.066 us; speedup 1.0000x reference)
//
#include <hip/hip_runtime.h>
#include <cstdint>
#include <cstddef>

#define B_   128
#define NF_  64
#define L_   4096
#define K_   64
#define NG_  400

#define GP_    6                       // g partitions (grid.x): 768 blocks = 3/CU
#define PADF_  128                     // zero pad each side (window overhang <= 99)
#define ROWPF_ (PADF_ + L_ + PADF_)    // 4352 floats per padded row (17408 B)

constexpr float STEP = 4096.0f / 4095.0f;              // linspace(0,4096,4096) step
constexpr float NEGC = -1.4426950408889634f / 512.0f;  // -log2(e)/(2*sigma^2), sigma=16

// async global->LDS, 16B per lane, wave-uniform LDS base + lane*16
__device__ __forceinline__ void dma16(const float* g, float* l) {
    __builtin_amdgcn_global_load_lds(
        (const __attribute__((address_space(1))) void*)g,
        (__attribute__((address_space(3))) void*)l, 16, 0, 0);
}

// ---------------------------------------------------------------------------
// Persistent filter kernel, DMA-pipelined (depth 2, 3-slot LDS ring).
// Block = (g-partition p, batch row b). 512 thr = 64 filters x 8 f4-slots.
// LDS = 3 x 17.4KB = 51KB -> 3 blocks/CU, 24 waves/CU.
// Per g-iteration: vmcnt(2) [tile i ready, tile i+1 still in flight] ->
// raw s_barrier -> load mu/sc(i) -> DMA tile i+2 -> weights (24 exp2, regs)
// -> 6x ds_read_b128 dot -> acc. Loads NEVER drain to 0 in the loop.
// ---------------------------------------------------------------------------
__global__ __launch_bounds__(512, 6) void filt_kernel(
    const float* __restrict__ X, const float* __restrict__ mus,
    const float* __restrict__ amps, float* __restrict__ part)
{
    const int p    = blockIdx.x;
    const int b    = blockIdx.y;
    const int t    = threadIdx.x;
    const int f    = t >> 3;          // filter 0..63
    const int i8   = t & 7;           // window float4 slot 0..7
    const int w    = t >> 6;          // wave 0..7
    const int lane = t & 63;

    // partition p's g range: 4 parts of 67, 2 parts of 66  (4*67+2*66=400)
    const int cnt = (p < 4) ? 67 : 66;
    const int gs  = (p < 4) ? p * 67 : 268 + (p - 4) * 66;

    __shared__ __align__(16) float Xs[3][ROWPF_];

    // zero the pads of all 3 slots once (32 f4 front + 32 f4 back each)
    if (t < 192) {
        const int bu = t >> 6, k = t & 63;
        float4* pr = (float4*)Xs[bu];
        const float4 z{0.f, 0.f, 0.f, 0.f};
        if (k < 32) pr[k] = z;
        else        pr[1056 + (k - 32)] = z;       // 4224/4 = 1056
    }
    __syncthreads();   // pads visible; no DMA outstanding yet (cheap drain)

    const float* __restrict__ Xrow = X + (size_t)b * NG_ * L_;
    const int chunk = w * 2;          // each wave stages chunks {chunk, chunk+1}

    // ---- prologue: DMA tiles 0 and 1 into slots 0 and 1 ----
    {
        const float* r0 = Xrow + (size_t)(gs + 0) * L_;
        dma16(r0 + (chunk    ) * 256 + lane * 4, &Xs[0][PADF_ + (chunk    ) * 256]);
        dma16(r0 + (chunk + 1) * 256 + lane * 4, &Xs[0][PADF_ + (chunk + 1) * 256]);
        const float* r1 = Xrow + (size_t)(gs + 1) * L_;
        dma16(r1 + (chunk    ) * 256 + lane * 4, &Xs[1][PADF_ + (chunk    ) * 256]);
        dma16(r1 + (chunk + 1) * 256 + lane * 4, &Xs[1][PADF_ + (chunk + 1) * 256]);
    }

    float acc = 0.0f;
    int slot = 0;
    for (int it = 0; it < cnt; ++it) {
        const int g = gs + it;

        // tile `it` resident (its 2 DMAs are the oldest outstanding);
        // allow tile it+1's 2 DMAs to stay in flight across the barrier
        asm volatile("s_waitcnt vmcnt(2)" ::: "memory");
        __builtin_amdgcn_s_barrier();
        __builtin_amdgcn_sched_barrier(0);

        // mu/sc for current tile — issued BEFORE next DMA so the compiler's
        // auto-wait for them is counted (keeps the DMA pair outstanding)
        const float mu = mus [f * NG_ + g];
        const float sc = amps[f * NG_ + g] * (1.0f / 4096.0f);
        __builtin_amdgcn_sched_barrier(0);

        if (it + 2 < cnt) {
            const float* rn = Xrow + (size_t)(g + 2) * L_;
            const int ns = (slot + 2 >= 3) ? slot - 1 : slot + 2;   // (slot+2)%3
            dma16(rn + (chunk    ) * 256 + lane * 4, &Xs[ns][PADF_ + (chunk    ) * 256]);
            dma16(rn + (chunk + 1) * 256 + lane * 4, &Xs[ns][PADF_ + (chunk + 1) * 256]);
        }
        __builtin_amdgcn_sched_barrier(0);

        // 24 Gaussian window weights (registers)
        const int   l0 = (((int)mu) - 96) & ~3;        // 16B-aligned start
        const float bx = fmaf((float)(l0 + 4 * i8), STEP, -mu);
        float wgt[6][4];
#pragma unroll
        for (int c = 0; c < 6; ++c)
#pragma unroll
            for (int j = 0; j < 4; ++j) {
                const float d = bx + (float)(32 * c + j) * STEP;
                wgt[c][j] = exp2f(NEGC * d * d);
            }

        // windowed dot: 8 consecutive lanes read 8 consecutive float4
        // -> all 32 banks exactly once, conflict-free
        const float* xp = Xs[slot] + PADF_ + l0 + 4 * i8;
        float dsum = 0.0f;
#pragma unroll
        for (int c = 0; c < 6; ++c) {
            const float4 a = *(const float4*)(xp + 32 * c);
            dsum = fmaf(a.x, wgt[c][0], fmaf(a.y, wgt[c][1],
                   fmaf(a.z, wgt[c][2], fmaf(a.w, wgt[c][3], dsum))));
        }
        acc = fmaf(sc, dsum, acc);

        slot = (slot == 2) ? 0 : slot + 1;
    }

    // reduce across the 8 lanes sharing this filter
#pragma unroll
    for (int d = 1; d < 8; d <<= 1) acc += __shfl_xor(acc, d);
    if (i8 == 0) part[((size_t)p * B_ + b) * NF_ + f] = acc;
}

// ---------------------------------------------------------------------------
// MLP head: sums GP_ partials, elu/reparam + 3 small GEMVs (exact gelu).
// Widened to grid (B_, 4): q-slice owns 100 of the 400 output gaussians;
// the tiny front (mu/log_sig/latent/h) is recomputed per slice, q==0 stores.
// out layout: coms[128*400] | pred[128*400] | mu[128*64] | log_sig[128*64]
// ---------------------------------------------------------------------------
__device__ __forceinline__ float gelu_exact(float x) {
    return 0.5f * x * (1.0f + erff(x * 0.70710678118654752f));
}

__global__ __launch_bounds__(256) void head_kernel(
    const float* __restrict__ part, const float* __restrict__ eps,
    const float* __restrict__ Wmu,  const float* __restrict__ bmu,
    const float* __restrict__ Wsig, const float* __restrict__ bsig,
    const float* __restrict__ W01,  const float* __restrict__ b01,
    const float* __restrict__ W1,   const float* __restrict__ b1,
    const float* __restrict__ W2,   const float* __restrict__ b2,
    float* __restrict__ out)
{
    const int b = blockIdx.x;
    const int q = blockIdx.y;
    const int t = threadIdx.x;
    __shared__ float fil[NF_], lat[K_], hh[K_];

    if (t < NF_) {
        float s = 0.f;
#pragma unroll
        for (int pp = 0; pp < GP_; ++pp)
            s += part[((size_t)pp * B_ + b) * NF_ + t];
        fil[t] = s;
    }
    __syncthreads();

    if (t < K_) {
        float am = bmu[t], as = bsig[t];
#pragma unroll 8
        for (int fj = 0; fj < NF_; ++fj) {
            float x = fil[fj];
            am = fmaf(x, Wmu [t * NF_ + fj], am);
            as = fmaf(x, Wsig[t * NF_ + fj], as);
        }
        float muv = am > 0.0f ? am : expm1f(am);
        float lsv = as > 0.0f ? as : expm1f(as);
        if (q == 0) {
            out[2 * B_ * NG_            + b * K_ + t] = muv;   // mu
            out[2 * B_ * NG_ + B_ * K_  + b * K_ + t] = lsv;   // log_sig
        }
        lat[t] = fmaf(eps[b * K_ + t], expf(lsv), muv);
    }
    __syncthreads();

    if (t < K_) {
        float a = b01[t];
#pragma unroll 8
        for (int j = 0; j < K_; ++j) a = fmaf(lat[j], W01[t * K_ + j], a);
        hh[t] = gelu_exact(a);
    }
    __syncthreads();

    const int n0 = q * 100, n1 = n0 + 100;
    for (int n = n0 + t; n < n1; n += 256) {
        float a1 = b1[n], a2 = b2[n];
#pragma unroll 8
        for (int k = 0; k < K_; ++k) {
            float hk = hh[k];
            a1 = fmaf(hk, W1[n * K_ + k], a1);
            a2 = fmaf(hk, W2[n * K_ + k], a2);
        }
        out[            b * NG_ + n] = gelu_exact(a1);   // coms
        out[B_ * NG_ +  b * NG_ + n] = gelu_exact(a2);   // pred_num_spikes
    }
}

extern "C" void kernel_launch(void* const* d_in, const int* in_sizes, int n_in,
                              void* d_out, int out_size, void* d_ws, size_t ws_size,
                              hipStream_t stream) {
    const float* X    = (const float*)d_in[0];
    const float* eps  = (const float*)d_in[1];
    const float* mus  = (const float*)d_in[2];
    const float* amps = (const float*)d_in[3];
    const float* Wmu  = (const float*)d_in[4];
    const float* bmu  = (const float*)d_in[5];
    const float* Wsig = (const float*)d_in[6];
    const float* bsig = (const float*)d_in[7];
    const float* W01  = (const float*)d_in[8];
    const float* b01  = (const float*)d_in[9];
    const float* W1   = (const float*)d_in[10];
    const float* b1   = (const float*)d_in[11];
    const float* W2   = (const float*)d_in[12];
    const float* b2   = (const float*)d_in[13];

    float* out  = (float*)d_out;
    float* part = (float*)d_ws;   // GP_*B_*NF_ f32 partials (fully overwritten)

    filt_kernel<<<dim3(GP_, B_), 512, 0, stream>>>(X, mus, amps, part);
    head_kernel<<<dim3(B_, 4), 256, 0, stream>>>(part, eps, Wmu, bmu, Wsig, bsig,
                                                 W01, b01, W1, b1, W2, b2, out);
}

// Round 6
// 212.973 us; speedup vs baseline: 1.0004x; 1.0004x over previous
//
#include <hip/hip_runtime.h>
#include <cstdint>
#include <cstddef>

#define B_   128
#define NF_  64
#define L_   4096
#define K_   64
#define NG_  400

#define GP_    6                       // g partitions (grid.x): 768 blocks = 3/CU
#define PADF_  128                     // zero pad each side (window overhang <= 99)
#define ROWPF_ (PADF_ + L_ + PADF_)    // 4352 floats per padded row (17408 B)

constexpr float STEP = 4096.0f / 4095.0f;              // linspace(0,4096,4096) step
constexpr float NEGC = -1.4426950408889634f / 512.0f;  // -log2(e)/(2*sigma^2), sigma=16

// async global->LDS, 16B per lane, wave-uniform LDS base + lane*16
__device__ __forceinline__ void dma16(const float* g, float* l) {
    __builtin_amdgcn_global_load_lds(
        (const __attribute__((address_space(1))) void*)g,
        (__attribute__((address_space(3))) void*)l, 16, 0, 0);
}

// ---------------------------------------------------------------------------
// Persistent filter kernel, DMA-pipelined (depth 2, 3-slot LDS ring).
// Block = (g-partition p, batch row b). 512 thr = 64 filters x 8 f4-slots.
// LDS = 3 x 17.4KB = 51KB -> 3 blocks/CU, 24 waves/CU.
// Per g-iteration: vmcnt(2) [tile i ready, tile i+1 still in flight] ->
// raw s_barrier -> load mu/sc(i) -> DMA tile i+2 -> weights (24 exp2, regs)
// -> 6x ds_read_b128 dot -> acc. Loads NEVER drain to 0 in the loop.
// ---------------------------------------------------------------------------
__global__ __launch_bounds__(512, 6) void filt_kernel(
    const float* __restrict__ X, const float* __restrict__ mus,
    const float* __restrict__ amps, float* __restrict__ part)
{
    const int p    = blockIdx.x;
    const int b    = blockIdx.y;
    const int t    = threadIdx.x;
    const int f    = t >> 3;          // filter 0..63
    const int i8   = t & 7;           // window float4 slot 0..7
    const int w    = t >> 6;          // wave 0..7
    const int lane = t & 63;

    // partition p's g range: 4 parts of 67, 2 parts of 66  (4*67+2*66=400)
    const int cnt = (p < 4) ? 67 : 66;
    const int gs  = (p < 4) ? p * 67 : 268 + (p - 4) * 66;

    __shared__ __align__(16) float Xs[3][ROWPF_];

    // zero the pads of all 3 slots once (32 f4 front + 32 f4 back each)
    if (t < 192) {
        const int bu = t >> 6, k = t & 63;
        float4* pr = (float4*)Xs[bu];
        const float4 z{0.f, 0.f, 0.f, 0.f};
        if (k < 32) pr[k] = z;
        else        pr[1056 + (k - 32)] = z;       // 4224/4 = 1056
    }
    __syncthreads();   // pads visible; no DMA outstanding yet (cheap drain)

    const float* __restrict__ Xrow = X + (size_t)b * NG_ * L_;
    const int chunk = w * 2;          // each wave stages chunks {chunk, chunk+1}

    // ---- prologue: DMA tiles 0 and 1 into slots 0 and 1 ----
    {
        const float* r0 = Xrow + (size_t)(gs + 0) * L_;
        dma16(r0 + (chunk    ) * 256 + lane * 4, &Xs[0][PADF_ + (chunk    ) * 256]);
        dma16(r0 + (chunk + 1) * 256 + lane * 4, &Xs[0][PADF_ + (chunk + 1) * 256]);
        const float* r1 = Xrow + (size_t)(gs + 1) * L_;
        dma16(r1 + (chunk    ) * 256 + lane * 4, &Xs[1][PADF_ + (chunk    ) * 256]);
        dma16(r1 + (chunk + 1) * 256 + lane * 4, &Xs[1][PADF_ + (chunk + 1) * 256]);
    }

    float acc = 0.0f;
    int slot = 0;
    for (int it = 0; it < cnt; ++it) {
        const int g = gs + it;

        // tile `it` resident (its 2 DMAs are the oldest outstanding);
        // allow tile it+1's 2 DMAs to stay in flight across the barrier
        asm volatile("s_waitcnt vmcnt(2)" ::: "memory");
        __builtin_amdgcn_s_barrier();
        __builtin_amdgcn_sched_barrier(0);

        // mu/sc for current tile — issued BEFORE next DMA so the compiler's
        // auto-wait for them is counted (keeps the DMA pair outstanding)
        const float mu = mus [f * NG_ + g];
        const float sc = amps[f * NG_ + g] * (1.0f / 4096.0f);
        __builtin_amdgcn_sched_barrier(0);

        if (it + 2 < cnt) {
            const float* rn = Xrow + (size_t)(g + 2) * L_;
            const int ns = (slot + 2 >= 3) ? slot - 1 : slot + 2;   // (slot+2)%3
            dma16(rn + (chunk    ) * 256 + lane * 4, &Xs[ns][PADF_ + (chunk    ) * 256]);
            dma16(rn + (chunk + 1) * 256 + lane * 4, &Xs[ns][PADF_ + (chunk + 1) * 256]);
        }
        __builtin_amdgcn_sched_barrier(0);

        // 24 Gaussian window weights (registers)
        const int   l0 = (((int)mu) - 96) & ~3;        // 16B-aligned start
        const float bx = fmaf((float)(l0 + 4 * i8), STEP, -mu);
        float wgt[6][4];
#pragma unroll
        for (int c = 0; c < 6; ++c)
#pragma unroll
            for (int j = 0; j < 4; ++j) {
                const float d = bx + (float)(32 * c + j) * STEP;
                wgt[c][j] = exp2f(NEGC * d * d);
            }

        // windowed dot: 8 consecutive lanes read 8 consecutive float4
        // -> all 32 banks exactly once, conflict-free
        const float* xp = Xs[slot] + PADF_ + l0 + 4 * i8;
        float dsum = 0.0f;
#pragma unroll
        for (int c = 0; c < 6; ++c) {
            const float4 a = *(const float4*)(xp + 32 * c);
            dsum = fmaf(a.x, wgt[c][0], fmaf(a.y, wgt[c][1],
                   fmaf(a.z, wgt[c][2], fmaf(a.w, wgt[c][3], dsum))));
        }
        acc = fmaf(sc, dsum, acc);

        slot = (slot == 2) ? 0 : slot + 1;
    }

    // reduce across the 8 lanes sharing this filter
#pragma unroll
    for (int d = 1; d < 8; d <<= 1) acc += __shfl_xor(acc, d);
    if (i8 == 0) part[((size_t)p * B_ + b) * NF_ + f] = acc;
}

// ---------------------------------------------------------------------------
// MLP head: sums GP_ partials, elu/reparam + 3 small GEMVs (exact gelu).
// Widened to grid (B_, 4): q-slice owns 100 of the 400 output gaussians;
// the tiny front (mu/log_sig/latent/h) is recomputed per slice, q==0 stores.
// out layout: coms[128*400] | pred[128*400] | mu[128*64] | log_sig[128*64]
// ---------------------------------------------------------------------------
__device__ __forceinline__ float gelu_exact(float x) {
    return 0.5f * x * (1.0f + erff(x * 0.70710678118654752f));
}

__global__ __launch_bounds__(256) void head_kernel(
    const float* __restrict__ part, const float* __restrict__ eps,
    const float* __restrict__ Wmu,  const float* __restrict__ bmu,
    const float* __restrict__ Wsig, const float* __restrict__ bsig,
    const float* __restrict__ W01,  const float* __restrict__ b01,
    const float* __restrict__ W1,   const float* __restrict__ b1,
    const float* __restrict__ W2,   const float* __restrict__ b2,
    float* __restrict__ out)
{
    const int b = blockIdx.x;
    const int q = blockIdx.y;
    const int t = threadIdx.x;
    __shared__ float fil[NF_], lat[K_], hh[K_];

    if (t < NF_) {
        float s = 0.f;
#pragma unroll
        for (int pp = 0; pp < GP_; ++pp)
            s += part[((size_t)pp * B_ + b) * NF_ + t];
        fil[t] = s;
    }
    __syncthreads();

    if (t < K_) {
        float am = bmu[t], as = bsig[t];
#pragma unroll 8
        for (int fj = 0; fj < NF_; ++fj) {
            float x = fil[fj];
            am = fmaf(x, Wmu [t * NF_ + fj], am);
            as = fmaf(x, Wsig[t * NF_ + fj], as);
        }
        float muv = am > 0.0f ? am : expm1f(am);
        float lsv = as > 0.0f ? as : expm1f(as);
        if (q == 0) {
            out[2 * B_ * NG_            + b * K_ + t] = muv;   // mu
            out[2 * B_ * NG_ + B_ * K_  + b * K_ + t] = lsv;   // log_sig
        }
        lat[t] = fmaf(eps[b * K_ + t], expf(lsv), muv);
    }
    __syncthreads();

    if (t < K_) {
        float a = b01[t];
#pragma unroll 8
        for (int j = 0; j < K_; ++j) a = fmaf(lat[j], W01[t * K_ + j], a);
        hh[t] = gelu_exact(a);
    }
    __syncthreads();

    const int n0 = q * 100, n1 = n0 + 100;
    for (int n = n0 + t; n < n1; n += 256) {
        float a1 = b1[n], a2 = b2[n];
#pragma unroll 8
        for (int k = 0; k < K_; ++k) {
            float hk = hh[k];
            a1 = fmaf(hk, W1[n * K_ + k], a1);
            a2 = fmaf(hk, W2[n * K_ + k], a2);
        }
        out[            b * NG_ + n] = gelu_exact(a1);   // coms
        out[B_ * NG_ +  b * NG_ + n] = gelu_exact(a2);   // pred_num_spikes
    }
}

extern "C" void kernel_launch(void* const* d_in, const int* in_sizes, int n_in,
                              void* d_out, int out_size, void* d_ws, size_t ws_size,
                              hipStream_t stream) {
    const float* X    = (const float*)d_in[0];
    const float* eps  = (const float*)d_in[1];
    const float* mus  = (const float*)d_in[2];
    const float* amps = (const float*)d_in[3];
    const float* Wmu  = (const float*)d_in[4];
    const float* bmu  = (const float*)d_in[5];
    const float* Wsig = (const float*)d_in[6];
    const float* bsig = (const float*)d_in[7];
    const float* W01  = (const float*)d_in[8];
    const float* b01  = (const float*)d_in[9];
    const float* W1   = (const float*)d_in[10];
    const float* b1   = (const float*)d_in[11];
    const float* W2   = (const float*)d_in[12];
    const float* b2   = (const float*)d_in[13];

    float* out  = (float*)d_out;
    float* part = (float*)d_ws;   // GP_*B_*NF_ f32 partials (fully overwritten)

    filt_kernel<<<dim3(GP_, B_), 512, 0, stream>>>(X, mus, amps, part);
    head_kernel<<<dim3(B_, 4), 256, 0, stream>>>(part, eps, Wmu, bmu, Wsig, bsig,
                                                 W01, b01, W1, b1, W2, b2, out);
}